// Round 3
// baseline (849.931 us; speedup 1.0000x reference)
//
#include <hip/hip_runtime.h>

#define N_NODES 100000
#define E_EDGES 1600000
#define E_TOT   1700000   // edges + self loops
#define FDIM    128       // F_IN and HEADS*HID
#define C2      10        // classes
#define NEG     0.2f
#define LOG2E   1.44269504088896f

// ---------------- CSR build ----------------
__global__ __launch_bounds__(256) void k_deg(const int* __restrict__ ei, int* __restrict__ cnt) {
  int tid = blockIdx.x * 256 + threadIdx.x;
  if (tid >= E_TOT) return;
  int d = (tid < E_EDGES) ? ei[E_EDGES + tid] : (tid - E_EDGES);
  atomicAdd(&cnt[d], 1);
}

#define SCAN_ITEMS 8
#define SCAN_CHUNK 2048
#define SCAN_NBLK  ((N_NODES + SCAN_CHUNK - 1) / SCAN_CHUNK)   // 49

__global__ __launch_bounds__(256) void k_scan1(const int* __restrict__ cnt, int* __restrict__ bsum) {
  int b = blockIdx.x, t = threadIdx.x;
  int base = b * SCAN_CHUNK + t * SCAN_ITEMS;
  int s = 0;
#pragma unroll
  for (int i = 0; i < SCAN_ITEMS; i++) {
    int idx = base + i;
    if (idx < N_NODES) s += cnt[idx];
  }
  __shared__ int sd[256];
  sd[t] = s; __syncthreads();
  for (int o = 128; o > 0; o >>= 1) {
    if (t < o) sd[t] += sd[t + o];
    __syncthreads();
  }
  if (t == 0) bsum[b] = sd[0];
}

__global__ __launch_bounds__(64) void k_scan2(const int* __restrict__ bsum, int* __restrict__ boff) {
  int t = threadIdx.x;
  int v = (t < SCAN_NBLK) ? bsum[t] : 0;
  int orig = v;
  for (int o = 1; o < 64; o <<= 1) {
    int u = __shfl_up(v, o);
    if (t >= o) v += u;
  }
  if (t < SCAN_NBLK) boff[t] = v - orig;
}

// writes exclusive prefix into row_ptr AND into cnt (cnt becomes the scatter fill cursor)
__global__ __launch_bounds__(256) void k_scan3(int* __restrict__ cnt, const int* __restrict__ boff,
                                               int* __restrict__ row_ptr) {
  int b = blockIdx.x, t = threadIdx.x;
  int base = b * SCAN_CHUNK + t * SCAN_ITEMS;
  int vals[SCAN_ITEMS]; int ts = 0;
#pragma unroll
  for (int i = 0; i < SCAN_ITEMS; i++) {
    int idx = base + i;
    vals[i] = (idx < N_NODES) ? cnt[idx] : 0;
    ts += vals[i];
  }
  __shared__ int sd[256];
  sd[t] = ts; __syncthreads();
  for (int o = 1; o < 256; o <<= 1) {
    int v = 0;
    if (t >= o) v = sd[t - o];
    __syncthreads();
    sd[t] += v;
    __syncthreads();
  }
  int run = boff[b] + sd[t] - ts;   // exclusive prefix for this thread's first item
#pragma unroll
  for (int i = 0; i < SCAN_ITEMS; i++) {
    int idx = base + i;
    if (idx < N_NODES) { row_ptr[idx] = run; cnt[idx] = run; }
    run += vals[i];
  }
  if (b == 0 && t == 0) row_ptr[N_NODES] = E_TOT;
}

__global__ __launch_bounds__(256) void k_scatter(const int* __restrict__ ei, int* __restrict__ fill,
                                                 int* __restrict__ colA) {
  int tid = blockIdx.x * 256 + threadIdx.x;
  if (tid >= E_TOT) return;
  int s, d;
  if (tid < E_EDGES) { s = ei[tid]; d = ei[E_EDGES + tid]; }
  else { s = tid - E_EDGES; d = s; }
  int pos = atomicAdd(&fill[d], 1);
  colA[pos] = s;
}

// Canonicalize CSR rows: sort each row's sources ascending so the FP
// accumulation order is bit-identical on every call (atomic scatter order is
// timing-dependent; online softmax is order-sensitive at ~1e-4 relative).
__global__ __launch_bounds__(256) void k_sort(const int* __restrict__ row_ptr, int* __restrict__ colA) {
  int node = blockIdx.x * 256 + threadIdx.x;
  if (node >= N_NODES) return;
  int beg = row_ptr[node], end = row_ptr[node + 1];
  for (int i = beg + 1; i < end; i++) {
    int v = colA[i];
    int j = i - 1;
    while (j >= beg && colA[j] > v) { colA[j + 1] = colA[j]; j--; }
    colA[j + 1] = v;
  }
}

// ---------------- Layer-1 GEMM: Hl = x@W1l, Hr = x@W1r (both 128->128) ----------------
__global__ __launch_bounds__(256) void k_gemm1(const float* __restrict__ x, const float* __restrict__ Wl,
                                               const float* __restrict__ Wr,
                                               float* __restrict__ Hl, float* __restrict__ Hr) {
  __shared__ float xs[64 * FDIM];
  int row0 = blockIdx.x * 64;
  int t = threadIdx.x;
  int avail = N_NODES - row0;
  const float4* xg = (const float4*)(x + (size_t)row0 * FDIM);
  float4* xs4 = (float4*)xs;
  if (avail >= 64) {
#pragma unroll
    for (int i = 0; i < 8; i++) xs4[t + i * 256] = xg[t + i * 256];
  } else {
#pragma unroll
    for (int i = 0; i < 8; i++) {
      int idx = t + i * 256;
      int r = idx >> 5;               // 32 float4 per row
      float4 v = make_float4(0.f, 0.f, 0.f, 0.f);
      if (r < avail) v = xg[idx];
      xs4[idx] = v;
    }
  }
  __syncthreads();
  int c  = t & 63;
  int rg = (t >> 6) * 16;
  float al0[16], al1[16], ar0[16], ar1[16];
#pragma unroll
  for (int r = 0; r < 16; r++) { al0[r] = 0.f; al1[r] = 0.f; ar0[r] = 0.f; ar1[r] = 0.f; }
  for (int k4 = 0; k4 < 32; k4++) {
    int k = k4 * 4;
    float wl0[4], wl1[4], wr0[4], wr1[4];
#pragma unroll
    for (int j = 0; j < 4; j++) {
      wl0[j] = Wl[(k + j) * FDIM + c];
      wl1[j] = Wl[(k + j) * FDIM + c + 64];
      wr0[j] = Wr[(k + j) * FDIM + c];
      wr1[j] = Wr[(k + j) * FDIM + c + 64];
    }
#pragma unroll
    for (int r = 0; r < 16; r++) {
      float4 xv = *(const float4*)&xs[(rg + r) * FDIM + k];   // wave-broadcast, conflict-free
      al0[r] += xv.x * wl0[0] + xv.y * wl0[1] + xv.z * wl0[2] + xv.w * wl0[3];
      al1[r] += xv.x * wl1[0] + xv.y * wl1[1] + xv.z * wl1[2] + xv.w * wl1[3];
      ar0[r] += xv.x * wr0[0] + xv.y * wr0[1] + xv.z * wr0[2] + xv.w * wr0[3];
      ar1[r] += xv.x * wr1[0] + xv.y * wr1[1] + xv.z * wr1[2] + xv.w * wr1[3];
    }
  }
#pragma unroll
  for (int r = 0; r < 16; r++) {
    int row = row0 + rg + r;
    if (row < N_NODES) {
      size_t o = (size_t)row * FDIM;
      Hl[o + c] = al0[r]; Hl[o + c + 64] = al1[r];
      Hr[o + c] = ar0[r]; Hr[o + c + 64] = ar1[r];
    }
  }
}

// ---------------- Layer-1 aggregation (online softmax over incoming edges) ----------------
// 1 wave per node; lane holds channels {2l, 2l+1}; head = lane/16; fused ReLU + bias.
__global__ __launch_bounds__(256) void k_agg1(const float* __restrict__ Hl, const float* __restrict__ Hr,
                                              const int* __restrict__ row_ptr, const int* __restrict__ colA,
                                              const float* __restrict__ att, const float* __restrict__ bias,
                                              float* __restrict__ outp) {
  int node = blockIdx.x * 4 + (threadIdx.x >> 6);
  if (node >= N_NODES) return;
  int lane = threadIdx.x & 63;
  int c0 = 2 * lane;
  float2 xr = *(const float2*)&Hr[(size_t)node * FDIM + c0];
  float a0 = att[c0] * LOG2E;        // scores scaled by log2(e) -> use exp2
  float a1 = att[c0 + 1] * LOG2E;
  int beg = row_ptr[node], end = row_ptr[node + 1];
  float m = -__builtin_inff(), l = 0.f, ax = 0.f, ay = 0.f;
  for (int j = beg; j < end; j++) {
    int s = colA[j];
    float2 xl = *(const float2*)&Hl[(size_t)s * FDIM + c0];
    float tx = xl.x + xr.x, ty = xl.y + xr.y;
    tx = tx > 0.f ? tx : NEG * tx;
    ty = ty > 0.f ? ty : NEG * ty;
    float p = a0 * tx + a1 * ty;
    p += __shfl_xor(p, 1);
    p += __shfl_xor(p, 2);
    p += __shfl_xor(p, 4);
    p += __shfl_xor(p, 8);                            // per-head score (16 lanes)
    float mn = fmaxf(m, p);
    float f = __builtin_amdgcn_exp2f(m - mn);         // first iter: exp2(-inf)=0
    float w = __builtin_amdgcn_exp2f(p - mn);
    l  = l  * f + w;
    ax = ax * f + w * xl.x;
    ay = ay * f + w * xl.y;
    m = mn;
  }
  float inv = 1.f / l;
  float ox = fmaxf(ax * inv + bias[c0],     0.f);     // fused ReLU
  float oy = fmaxf(ay * inv + bias[c0 + 1], 0.f);
  *(float2*)&outp[(size_t)node * FDIM + c0] = make_float2(ox, oy);
}

// ---------------- Layer-2 GEMM: yl = h@W2l, yr = h@W2r (128->10 each) ----------------
__global__ __launch_bounds__(256) void k_gemm2(const float* __restrict__ h, const float* __restrict__ Wl,
                                               const float* __restrict__ Wr,
                                               float* __restrict__ yl, float* __restrict__ yr) {
  __shared__ float xs[64 * FDIM];
  int row0 = blockIdx.x * 64;
  int t = threadIdx.x;
  int avail = N_NODES - row0;
  const float4* xg = (const float4*)(h + (size_t)row0 * FDIM);
  float4* xs4 = (float4*)xs;
  if (avail >= 64) {
#pragma unroll
    for (int i = 0; i < 8; i++) xs4[t + i * 256] = xg[t + i * 256];
  } else {
#pragma unroll
    for (int i = 0; i < 8; i++) {
      int idx = t + i * 256;
      int r = idx >> 5;
      float4 v = make_float4(0.f, 0.f, 0.f, 0.f);
      if (r < avail) v = xg[idx];
      xs4[idx] = v;
    }
  }
  __syncthreads();
  int c  = t & 31;            // 0..9 -> Wl col c ; 10..19 -> Wr col c-10 ; rest idle
  int rg = (t >> 5) * 8;      // 8 groups x 8 rows
  bool isl = c < C2;
  bool act = c < 2 * C2;
  const float* W = isl ? Wl : Wr;
  int cc = isl ? c : c - C2;
  float acc[8];
#pragma unroll
  for (int r = 0; r < 8; r++) acc[r] = 0.f;
  if (act) {
    for (int k4 = 0; k4 < 32; k4++) {
      int k = k4 * 4;
      float w[4];
#pragma unroll
      for (int j = 0; j < 4; j++) w[j] = W[(k + j) * C2 + cc];
#pragma unroll
      for (int r = 0; r < 8; r++) {
        float4 xv = *(const float4*)&xs[(rg + r) * FDIM + k];
        acc[r] += xv.x * w[0] + xv.y * w[1] + xv.z * w[2] + xv.w * w[3];
      }
    }
#pragma unroll
    for (int r = 0; r < 8; r++) {
      int row = row0 + rg + r;
      if (row < N_NODES) {
        float* Y = isl ? yl : yr;
        Y[(size_t)row * C2 + cc] = acc[r];
      }
    }
  }
}

// ---------------- Layer-2 aggregation: 16-lane group per node, C2=10 channels ----------------
__global__ __launch_bounds__(256) void k_agg2(const float* __restrict__ yl, const float* __restrict__ yr,
                                              const int* __restrict__ row_ptr, const int* __restrict__ colA,
                                              const float* __restrict__ att, const float* __restrict__ bias,
                                              float* __restrict__ outp) {
  int node = blockIdx.x * 16 + (threadIdx.x >> 4);
  if (node >= N_NODES) return;
  int lane = threadIdx.x & 15;
  bool act = lane < C2;
  float xr = act ? yr[(size_t)node * C2 + lane] : 0.f;
  float a  = act ? att[lane] * LOG2E : 0.f;
  int beg = row_ptr[node], end = row_ptr[node + 1];
  float m = -__builtin_inff(), l = 0.f, acc = 0.f;
  for (int j = beg; j < end; j++) {
    int s = colA[j];
    float xl = act ? yl[(size_t)s * C2 + lane] : 0.f;
    float t = xl + xr;
    t = t > 0.f ? t : NEG * t;
    float p = a * t;
    p += __shfl_xor(p, 1);
    p += __shfl_xor(p, 2);
    p += __shfl_xor(p, 4);
    p += __shfl_xor(p, 8);
    float mn = fmaxf(m, p);
    float f = __builtin_amdgcn_exp2f(m - mn);
    float w = __builtin_amdgcn_exp2f(p - mn);
    l   = l   * f + w;
    acc = acc * f + w * xl;
    m = mn;
  }
  if (act) outp[(size_t)node * C2 + lane] = acc / l + bias[lane];
}

extern "C" void kernel_launch(void* const* d_in, const int* in_sizes, int n_in,
                              void* d_out, int out_size, void* d_ws, size_t ws_size,
                              hipStream_t stream) {
  const float* x    = (const float*)d_in[0];
  const int*   ei   = (const int*)d_in[1];   // [2,E] int
  const float* W1l  = (const float*)d_in[2];
  const float* W1r  = (const float*)d_in[3];
  const float* att1 = (const float*)d_in[4];
  const float* b1   = (const float*)d_in[5];
  const float* W2l  = (const float*)d_in[6];
  const float* W2r  = (const float*)d_in[7];
  const float* att2 = (const float*)d_in[8];
  const float* b2   = (const float*)d_in[9];
  float* out = (float*)d_out;

  char* ws = (char*)d_ws;
  size_t off = 0;
  auto take = [&](size_t bytes) -> char* {
    char* p = ws + off;
    off = (off + bytes + 511) & ~(size_t)511;
    return p;
  };
  float* Hl      = (float*)take((size_t)N_NODES * FDIM * sizeof(float));   // 51.2 MB
  float* Hr      = (float*)take((size_t)N_NODES * FDIM * sizeof(float));   // 51.2 MB
  float* H1      = (float*)take((size_t)N_NODES * FDIM * sizeof(float));   // 51.2 MB
  float* yl      = (float*)take((size_t)N_NODES * C2 * sizeof(float));     // 4 MB
  float* yr      = (float*)take((size_t)N_NODES * C2 * sizeof(float));     // 4 MB
  int*   cnt     = (int*)take((size_t)N_NODES * sizeof(int));
  int*   row_ptr = (int*)take((size_t)(N_NODES + 1) * sizeof(int));
  int*   colA    = (int*)take((size_t)E_TOT * sizeof(int));
  int*   bsum    = (int*)take(256);
  int*   boff    = (int*)take(256);
  if (off > ws_size) return;   // insufficient workspace — bail (bench will flag)

  (void)hipMemsetAsync(cnt, 0, (size_t)N_NODES * sizeof(int), stream);
  k_deg    <<<(E_TOT + 255) / 256, 256, 0, stream>>>(ei, cnt);
  k_scan1  <<<SCAN_NBLK, 256, 0, stream>>>(cnt, bsum);
  k_scan2  <<<1, 64, 0, stream>>>(bsum, boff);
  k_scan3  <<<SCAN_NBLK, 256, 0, stream>>>(cnt, boff, row_ptr);
  k_scatter<<<(E_TOT + 255) / 256, 256, 0, stream>>>(ei, cnt, colA);
  k_sort   <<<(N_NODES + 255) / 256, 256, 0, stream>>>(row_ptr, colA);
  k_gemm1  <<<(N_NODES + 63) / 64, 256, 0, stream>>>(x, W1l, W1r, Hl, Hr);
  k_agg1   <<<(N_NODES + 3) / 4, 256, 0, stream>>>(Hl, Hr, row_ptr, colA, att1, b1, H1);
  k_gemm2  <<<(N_NODES + 63) / 64, 256, 0, stream>>>(H1, W2l, W2r, yl, yr);
  k_agg2   <<<(N_NODES + 15) / 16, 256, 0, stream>>>(yl, yr, row_ptr, colA, att2, b2, out);
}

// Round 4
// 717.180 us; speedup vs baseline: 1.1851x; 1.1851x over previous
//
#include <hip/hip_runtime.h>

#define N_NODES 100000
#define E_EDGES 1600000
#define E_TOT   1700000   // edges + self loops
#define FDIM    128       // F_IN and HEADS*HID
#define C2      10        // classes
#define NEG     0.2f
#define LOG2E   1.44269504088896f

// ---------------- CSR build ----------------
__global__ __launch_bounds__(256) void k_deg(const int* __restrict__ ei, int* __restrict__ cnt) {
  int tid = blockIdx.x * 256 + threadIdx.x;
  if (tid >= E_TOT) return;
  int d = (tid < E_EDGES) ? ei[E_EDGES + tid] : (tid - E_EDGES);
  atomicAdd(&cnt[d], 1);
}

#define SCAN_ITEMS 8
#define SCAN_CHUNK 2048
#define SCAN_NBLK  ((N_NODES + SCAN_CHUNK - 1) / SCAN_CHUNK)   // 49

__global__ __launch_bounds__(256) void k_scan1(const int* __restrict__ cnt, int* __restrict__ bsum) {
  int b = blockIdx.x, t = threadIdx.x;
  int base = b * SCAN_CHUNK + t * SCAN_ITEMS;
  int s = 0;
#pragma unroll
  for (int i = 0; i < SCAN_ITEMS; i++) {
    int idx = base + i;
    if (idx < N_NODES) s += cnt[idx];
  }
  __shared__ int sd[256];
  sd[t] = s; __syncthreads();
  for (int o = 128; o > 0; o >>= 1) {
    if (t < o) sd[t] += sd[t + o];
    __syncthreads();
  }
  if (t == 0) bsum[b] = sd[0];
}

__global__ __launch_bounds__(64) void k_scan2(const int* __restrict__ bsum, int* __restrict__ boff) {
  int t = threadIdx.x;
  int v = (t < SCAN_NBLK) ? bsum[t] : 0;
  int orig = v;
  for (int o = 1; o < 64; o <<= 1) {
    int u = __shfl_up(v, o);
    if (t >= o) v += u;
  }
  if (t < SCAN_NBLK) boff[t] = v - orig;
}

__global__ __launch_bounds__(256) void k_scan3(int* __restrict__ cnt, const int* __restrict__ boff,
                                               int* __restrict__ row_ptr) {
  int b = blockIdx.x, t = threadIdx.x;
  int base = b * SCAN_CHUNK + t * SCAN_ITEMS;
  int vals[SCAN_ITEMS]; int ts = 0;
#pragma unroll
  for (int i = 0; i < SCAN_ITEMS; i++) {
    int idx = base + i;
    vals[i] = (idx < N_NODES) ? cnt[idx] : 0;
    ts += vals[i];
  }
  __shared__ int sd[256];
  sd[t] = ts; __syncthreads();
  for (int o = 1; o < 256; o <<= 1) {
    int v = 0;
    if (t >= o) v = sd[t - o];
    __syncthreads();
    sd[t] += v;
    __syncthreads();
  }
  int run = boff[b] + sd[t] - ts;
#pragma unroll
  for (int i = 0; i < SCAN_ITEMS; i++) {
    int idx = base + i;
    if (idx < N_NODES) { row_ptr[idx] = run; cnt[idx] = run; }
    run += vals[i];
  }
  if (b == 0 && t == 0) row_ptr[N_NODES] = E_TOT;
}

__global__ __launch_bounds__(256) void k_scatter(const int* __restrict__ ei, int* __restrict__ fill,
                                                 int* __restrict__ colA) {
  int tid = blockIdx.x * 256 + threadIdx.x;
  if (tid >= E_TOT) return;
  int s, d;
  if (tid < E_EDGES) { s = ei[tid]; d = ei[E_EDGES + tid]; }
  else { s = tid - E_EDGES; d = s; }
  int pos = atomicAdd(&fill[d], 1);
  colA[pos] = s;
}

// Canonicalize CSR rows (deterministic FP accumulation order every call).
// One WAVE per node: bitonic sort of <=64 sources via shfl_xor (21 steps).
// deg>64 is ~impossible at avg degree 17 but falls back to lane-0 insertion.
__global__ __launch_bounds__(256) void k_sort(const int* __restrict__ row_ptr, int* __restrict__ colA) {
  int node = blockIdx.x * 4 + (threadIdx.x >> 6);
  if (node >= N_NODES) return;
  int lane = threadIdx.x & 63;
  int beg = row_ptr[node], end = row_ptr[node + 1];
  int deg = end - beg;
  if (deg <= 1) return;
  if (deg <= 64) {
    int v = (lane < deg) ? colA[beg + lane] : 0x7FFFFFFF;
#pragma unroll
    for (int k = 2; k <= 64; k <<= 1) {
#pragma unroll
      for (int j = k >> 1; j > 0; j >>= 1) {
        int other = __shfl_xor(v, j);
        bool up = ((lane & k) == 0);
        bool lower = ((lane & j) == 0);
        int mn = min(v, other), mx = max(v, other);
        v = (lower == up) ? mn : mx;
      }
    }
    if (lane < deg) colA[beg + lane] = v;
  } else if (lane == 0) {
    for (int i = beg + 1; i < end; i++) {
      int v = colA[i];
      int j = i - 1;
      while (j >= beg && colA[j] > v) { colA[j + 1] = colA[j]; j--; }
      colA[j + 1] = v;
    }
  }
}

// ---------------- Layer-1 GEMM: Hl = x@W1l, Hr = x@W1r (both 128->128) ----------------
__global__ __launch_bounds__(256) void k_gemm1(const float* __restrict__ x, const float* __restrict__ Wl,
                                               const float* __restrict__ Wr,
                                               float* __restrict__ Hl, float* __restrict__ Hr) {
  __shared__ float xs[64 * FDIM];
  int row0 = blockIdx.x * 64;
  int t = threadIdx.x;
  int avail = N_NODES - row0;
  const float4* xg = (const float4*)(x + (size_t)row0 * FDIM);
  float4* xs4 = (float4*)xs;
  if (avail >= 64) {
#pragma unroll
    for (int i = 0; i < 8; i++) xs4[t + i * 256] = xg[t + i * 256];
  } else {
#pragma unroll
    for (int i = 0; i < 8; i++) {
      int idx = t + i * 256;
      int r = idx >> 5;
      float4 v = make_float4(0.f, 0.f, 0.f, 0.f);
      if (r < avail) v = xg[idx];
      xs4[idx] = v;
    }
  }
  __syncthreads();
  int c  = t & 63;
  int rg = (t >> 6) * 16;
  float al0[16], al1[16], ar0[16], ar1[16];
#pragma unroll
  for (int r = 0; r < 16; r++) { al0[r] = 0.f; al1[r] = 0.f; ar0[r] = 0.f; ar1[r] = 0.f; }
  for (int k4 = 0; k4 < 32; k4++) {
    int k = k4 * 4;
    float wl0[4], wl1[4], wr0[4], wr1[4];
#pragma unroll
    for (int j = 0; j < 4; j++) {
      wl0[j] = Wl[(k + j) * FDIM + c];
      wl1[j] = Wl[(k + j) * FDIM + c + 64];
      wr0[j] = Wr[(k + j) * FDIM + c];
      wr1[j] = Wr[(k + j) * FDIM + c + 64];
    }
#pragma unroll
    for (int r = 0; r < 16; r++) {
      float4 xv = *(const float4*)&xs[(rg + r) * FDIM + k];
      al0[r] += xv.x * wl0[0] + xv.y * wl0[1] + xv.z * wl0[2] + xv.w * wl0[3];
      al1[r] += xv.x * wl1[0] + xv.y * wl1[1] + xv.z * wl1[2] + xv.w * wl1[3];
      ar0[r] += xv.x * wr0[0] + xv.y * wr0[1] + xv.z * wr0[2] + xv.w * wr0[3];
      ar1[r] += xv.x * wr1[0] + xv.y * wr1[1] + xv.z * wr1[2] + xv.w * wr1[3];
    }
  }
#pragma unroll
  for (int r = 0; r < 16; r++) {
    int row = row0 + rg + r;
    if (row < N_NODES) {
      size_t o = (size_t)row * FDIM;
      Hl[o + c] = al0[r]; Hl[o + c + 64] = al1[r];
      Hr[o + c] = ar0[r]; Hr[o + c + 64] = ar1[r];
    }
  }
}

// ---------------- Layer-1 aggregation + fused layer-2 transform ----------------
// 1 wave/node; lane holds channels {2l,2l+1}; head = lane/16. Online softmax over
// sorted edges (sequential updates -> bit-identical every call). Unroll x4 so 4
// independent 512B gathers are in flight. Epilogue: h row -> LDS, 20 lanes compute
// yl = h@W2l, yr = h@W2r directly (H1 / separate gemm2 eliminated).
__global__ __launch_bounds__(256) void k_agg1(const float* __restrict__ Hl, const float* __restrict__ Hr,
                                              const int* __restrict__ row_ptr, const int* __restrict__ colA,
                                              const float* __restrict__ att, const float* __restrict__ bias,
                                              const float* __restrict__ W2l, const float* __restrict__ W2r,
                                              float* __restrict__ yl, float* __restrict__ yr) {
  __shared__ float hsh[4][FDIM];
  int w = threadIdx.x >> 6;
  int node = blockIdx.x * 4 + w;
  if (node >= N_NODES) return;
  int lane = threadIdx.x & 63;
  int c0 = 2 * lane;
  float2 xr = *(const float2*)&Hr[(size_t)node * FDIM + c0];
  float a0 = att[c0] * LOG2E;
  float a1 = att[c0 + 1] * LOG2E;
  int beg = row_ptr[node], end = row_ptr[node + 1];
  float m = -__builtin_inff(), l = 0.f, ax = 0.f, ay = 0.f;

  auto update = [&](float2 xl) {
    float tx = xl.x + xr.x, ty = xl.y + xr.y;
    tx = tx > 0.f ? tx : NEG * tx;
    ty = ty > 0.f ? ty : NEG * ty;
    float p = a0 * tx + a1 * ty;
    p += __shfl_xor(p, 1);
    p += __shfl_xor(p, 2);
    p += __shfl_xor(p, 4);
    p += __shfl_xor(p, 8);                      // per-head score (16 lanes)
    float mn = fmaxf(m, p);
    float f = __builtin_amdgcn_exp2f(m - mn);
    float ww = __builtin_amdgcn_exp2f(p - mn);
    l  = l  * f + ww;
    ax = ax * f + ww * xl.x;
    ay = ay * f + ww * xl.y;
    m = mn;
  };

  int j = beg;
  for (; j + 4 <= end; j += 4) {
    int s0 = colA[j], s1 = colA[j + 1], s2 = colA[j + 2], s3 = colA[j + 3];
    float2 x0 = *(const float2*)&Hl[(size_t)s0 * FDIM + c0];
    float2 x1 = *(const float2*)&Hl[(size_t)s1 * FDIM + c0];
    float2 x2 = *(const float2*)&Hl[(size_t)s2 * FDIM + c0];
    float2 x3 = *(const float2*)&Hl[(size_t)s3 * FDIM + c0];
    update(x0); update(x1); update(x2); update(x3);
  }
  for (; j < end; j++) {
    int s = colA[j];
    float2 xl = *(const float2*)&Hl[(size_t)s * FDIM + c0];
    update(xl);
  }

  float inv = 1.f / l;
  float ox = fmaxf(ax * inv + bias[c0],     0.f);   // fused ReLU
  float oy = fmaxf(ay * inv + bias[c0 + 1], 0.f);
  hsh[w][c0] = ox; hsh[w][c0 + 1] = oy;
  // intra-wave LDS RAW: DS ops retire in order for a wave; no barrier needed
  if (lane < 2 * C2) {
    bool isl = lane < C2;
    int cc = isl ? lane : lane - C2;
    const float* W = isl ? W2l : W2r;
    float acc = 0.f;
    const float4* h4 = (const float4*)hsh[w];
#pragma unroll
    for (int k4 = 0; k4 < 32; k4++) {
      float4 hv = h4[k4];
      int k = k4 * 4;
      acc = fmaf(hv.x, W[(k + 0) * C2 + cc], acc);
      acc = fmaf(hv.y, W[(k + 1) * C2 + cc], acc);
      acc = fmaf(hv.z, W[(k + 2) * C2 + cc], acc);
      acc = fmaf(hv.w, W[(k + 3) * C2 + cc], acc);
    }
    float* Y = isl ? yl : yr;
    Y[(size_t)node * C2 + cc] = acc;
  }
}

// ---------------- Layer-2 aggregation: 16-lane group per node, unroll x4 ----------------
__global__ __launch_bounds__(256) void k_agg2(const float* __restrict__ yl, const float* __restrict__ yr,
                                              const int* __restrict__ row_ptr, const int* __restrict__ colA,
                                              const float* __restrict__ att, const float* __restrict__ bias,
                                              float* __restrict__ outp) {
  int node = blockIdx.x * 16 + (threadIdx.x >> 4);
  if (node >= N_NODES) return;
  int lane = threadIdx.x & 15;
  bool act = lane < C2;
  float xr = act ? yr[(size_t)node * C2 + lane] : 0.f;
  float a  = act ? att[lane] * LOG2E : 0.f;
  int beg = row_ptr[node], end = row_ptr[node + 1];
  float m = -__builtin_inff(), l = 0.f, acc = 0.f;

  auto update = [&](float xl) {
    float t = xl + xr;
    t = t > 0.f ? t : NEG * t;
    float p = a * t;
    p += __shfl_xor(p, 1);
    p += __shfl_xor(p, 2);
    p += __shfl_xor(p, 4);
    p += __shfl_xor(p, 8);
    float mn = fmaxf(m, p);
    float f = __builtin_amdgcn_exp2f(m - mn);
    float w = __builtin_amdgcn_exp2f(p - mn);
    l   = l   * f + w;
    acc = acc * f + w * xl;
    m = mn;
  };

  int j = beg;
  for (; j + 4 <= end; j += 4) {
    int s0 = colA[j], s1 = colA[j + 1], s2 = colA[j + 2], s3 = colA[j + 3];
    float x0 = act ? yl[(size_t)s0 * C2 + lane] : 0.f;
    float x1 = act ? yl[(size_t)s1 * C2 + lane] : 0.f;
    float x2 = act ? yl[(size_t)s2 * C2 + lane] : 0.f;
    float x3 = act ? yl[(size_t)s3 * C2 + lane] : 0.f;
    update(x0); update(x1); update(x2); update(x3);
  }
  for (; j < end; j++) {
    int s = colA[j];
    float xl = act ? yl[(size_t)s * C2 + lane] : 0.f;
    update(xl);
  }
  if (act) outp[(size_t)node * C2 + lane] = acc / l + bias[lane];
}

extern "C" void kernel_launch(void* const* d_in, const int* in_sizes, int n_in,
                              void* d_out, int out_size, void* d_ws, size_t ws_size,
                              hipStream_t stream) {
  const float* x    = (const float*)d_in[0];
  const int*   ei   = (const int*)d_in[1];
  const float* W1l  = (const float*)d_in[2];
  const float* W1r  = (const float*)d_in[3];
  const float* att1 = (const float*)d_in[4];
  const float* b1   = (const float*)d_in[5];
  const float* W2l  = (const float*)d_in[6];
  const float* W2r  = (const float*)d_in[7];
  const float* att2 = (const float*)d_in[8];
  const float* b2   = (const float*)d_in[9];
  float* out = (float*)d_out;

  char* ws = (char*)d_ws;
  size_t off = 0;
  auto take = [&](size_t bytes) -> char* {
    char* p = ws + off;
    off = (off + bytes + 511) & ~(size_t)511;
    return p;
  };
  float* Hl      = (float*)take((size_t)N_NODES * FDIM * sizeof(float));   // 51.2 MB
  float* Hr      = (float*)take((size_t)N_NODES * FDIM * sizeof(float));   // 51.2 MB
  float* yl      = (float*)take((size_t)N_NODES * C2 * sizeof(float));     // 4 MB
  float* yr      = (float*)take((size_t)N_NODES * C2 * sizeof(float));     // 4 MB
  int*   cnt     = (int*)take((size_t)N_NODES * sizeof(int));
  int*   row_ptr = (int*)take((size_t)(N_NODES + 1) * sizeof(int));
  int*   colA    = (int*)take((size_t)E_TOT * sizeof(int));
  int*   bsum    = (int*)take(256);
  int*   boff    = (int*)take(256);
  if (off > ws_size) return;

  (void)hipMemsetAsync(cnt, 0, (size_t)N_NODES * sizeof(int), stream);
  k_deg    <<<(E_TOT + 255) / 256, 256, 0, stream>>>(ei, cnt);
  k_scan1  <<<SCAN_NBLK, 256, 0, stream>>>(cnt, bsum);
  k_scan2  <<<1, 64, 0, stream>>>(bsum, boff);
  k_scan3  <<<SCAN_NBLK, 256, 0, stream>>>(cnt, boff, row_ptr);
  k_scatter<<<(E_TOT + 255) / 256, 256, 0, stream>>>(ei, cnt, colA);
  k_sort   <<<(N_NODES + 3) / 4, 256, 0, stream>>>(row_ptr, colA);
  k_gemm1  <<<(N_NODES + 63) / 64, 256, 0, stream>>>(x, W1l, W1r, Hl, Hr);
  k_agg1   <<<(N_NODES + 3) / 4, 256, 0, stream>>>(Hl, Hr, row_ptr, colA, att1, b1, W2l, W2r, yl, yr);
  k_agg2   <<<(N_NODES + 15) / 16, 256, 0, stream>>>(yl, yr, row_ptr, colA, att2, b2, out);
}